// Round 4
// baseline (166.693 us; speedup 1.0000x reference)
//
#include <hip/hip_runtime.h>
#include <hip/hip_bf16.h>

// Problem constants (B=1 folded out)
constexpr int T = 8;     // frames
constexpr int C = 128;   // input channels
constexpr int N = 4096;  // H*W positions
constexpr int F = 64;    // feature dim

typedef __bf16 bf16x8 __attribute__((ext_vector_type(8)));
typedef __bf16 bf16x4 __attribute__((ext_vector_type(4)));
typedef float  f32x4  __attribute__((ext_vector_type(4)));

// ---------------------------------------------------------------------------
// Kernel 1: projections, LDS-free. All three computed as D[m=f][n'=npos]:
//   A-frag = W[f][c] (fp32 float4 loads -> bf16, L1-hot, identical per wave)
//   B-frag = x[c][npos] read DIRECTLY from global (8 scalar dword loads per
//            frag, 16-lane coalesced; each wave reads a disjoint 16-col slice
//            so x1/x2 are fetched exactly once -> no LDS, no barriers).
// Outputs: Q,K bf16 [t][n][F] (b64 stores); G bf16 [t][f][N] (scalar stores).
// Also zeroes d_out (poisoned 0xAA; attn accumulates atomically).
// ---------------------------------------------------------------------------
__global__ __launch_bounds__(256) void proj_kernel(
    const float* __restrict__ x1, const float* __restrict__ x2,
    const float* __restrict__ W1, const float* __restrict__ b1,
    const float* __restrict__ W2, const float* __restrict__ b2,
    const float* __restrict__ W3, const float* __restrict__ b3,
    __bf16* __restrict__ Qb, __bf16* __restrict__ Kb, __bf16* __restrict__ Gw,
    float* __restrict__ out)
{
    const int t   = blockIdx.x >> 6;    // 64 blocks per t, 64 npos per block
    const int nb  = blockIdx.x & 63;
    const int tid = threadIdx.x, wave = tid >> 6, lane = tid & 63;
    const int quad = lane >> 4, l16 = lane & 15;
    const int nw = nb * 64 + wave * 16;          // this wave's 16 positions

    // zero this block's 4096-float slice of d_out (512 blocks cover T*F*N)
    {
        f32x4* o4 = (f32x4*)out + (size_t)blockIdx.x * 1024;
#pragma unroll
        for (int i = 0; i < 4; ++i) o4[i * 256 + tid] = (f32x4){0.f, 0.f, 0.f, 0.f};
    }

    // x B-frags: B[k=c][n'=npos]; lane n'=l16, k = cc*32 + quad*8 + j
    bf16x8 xf1[4], xf2[4];
#pragma unroll
    for (int cc = 0; cc < 4; ++cc) {
#pragma unroll
        for (int j = 0; j < 8; ++j) {
            size_t off = ((size_t)t * C + cc * 32 + quad * 8 + j) * (size_t)N + nw + l16;
            xf1[cc][j] = (__bf16)x1[off];
            xf2[cc][j] = (__bf16)x2[off];
        }
    }

    const float* Ws[3] = {W1, W2, W3};
    const float* bs[3] = {b1, b2, b3};

#pragma unroll
    for (int p = 0; p < 3; ++p) {
        const float* W    = Ws[p];
        const float* bias = bs[p];
#pragma unroll
        for (int fb = 0; fb < 4; ++fb) {
            f32x4 acc = (f32x4){0.f, 0.f, 0.f, 0.f};
#pragma unroll
            for (int cc = 0; cc < 4; ++cc) {
                // A-frag: A[m=f][k=c], lane m=l16 -> f = fb*16+l16
                const f32x4* wp = (const f32x4*)&W[(fb * 16 + l16) * C + cc * 32 + quad * 8];
                f32x4 w0 = wp[0], w1 = wp[1];
                bf16x8 wf;
                wf[0] = (__bf16)w0[0]; wf[1] = (__bf16)w0[1];
                wf[2] = (__bf16)w0[2]; wf[3] = (__bf16)w0[3];
                wf[4] = (__bf16)w1[0]; wf[5] = (__bf16)w1[1];
                wf[6] = (__bf16)w1[2]; wf[7] = (__bf16)w1[3];
                bf16x8 xb = (p == 1) ? xf2[cc] : xf1[cc];
                acc = __builtin_amdgcn_mfma_f32_16x16x32_bf16(wf, xb, acc, 0, 0, 0);
            }
            // D: col = l16 -> npos = nw+l16 ; row = quad*4+r -> f = fb*16+quad*4+r
            if (p < 2) {
                __bf16* O = p ? Kb : Qb;
                bf16x4 ov;
#pragma unroll
                for (int r = 0; r < 4; ++r)
                    ov[r] = (__bf16)(acc[r] + bias[fb * 16 + quad * 4 + r]);
                *(bf16x4*)&O[((size_t)t * N + nw + l16) * F + fb * 16 + quad * 4] = ov;
            } else {
#pragma unroll
                for (int r = 0; r < 4; ++r) {
                    int f = fb * 16 + quad * 4 + r;
                    Gw[((size_t)t * F + f) * (size_t)N + nw + l16] = (__bf16)(acc[r] + bias[f]);
                }
            }
        }
    }
}

// ---------------------------------------------------------------------------
// Kernel 2: O[t][f][q] += sum_key relu(Q[q]·K[key]) * G[key][f]
// Block 256 = 4 waves; BM = 256 (64 q-rows per wave = 4 q-groups of 16).
// K-frag and G-frag LDS reads amortize over 4 q-groups. S-GEMM computes Sᵀ
// (b64 Sb writes); PV computes Oᵀ (direct atomic epilogue). KSPLIT=4 over
// the key range for grid size; next K/G tile register-prefetched.
// ---------------------------------------------------------------------------
constexpr int KSPLIT = 4;

__global__ __launch_bounds__(256) void attn_kernel(
    const __bf16* __restrict__ Qb, const __bf16* __restrict__ Kb,
    const __bf16* __restrict__ Gw, float* __restrict__ out)
{
    const int ks = blockIdx.x & (KSPLIT - 1);
    const int qb = (blockIdx.x / KSPLIT) & 15;   // N/256 = 16 q-blocks
    const int t  = blockIdx.x >> 6;
    const int q0 = qb * 256;

    constexpr int KS = 72;              // bf16 stride (144B rows)
    __shared__ __bf16 Kt[64 * KS];      // K tile [key][f]      (9216 B)
    __shared__ __bf16 Gt[64 * KS];      // G tile [f][key]      (9216 B)
    __shared__ __bf16 Sb[256 * KS];     // S [q][key]           (36864 B)

    const int tid = threadIdx.x, wave = tid >> 6, lane = tid & 63;
    const int quad = lane >> 4, l16 = lane & 15;

    // Q B-frags: B[n=q][k=f], q = q0 + wave*64 + qg*16 + l16
    bf16x8 qf[4][2];
#pragma unroll
    for (int qg = 0; qg < 4; ++qg) {
        const __bf16* qrow = &Qb[((size_t)t * N + q0 + wave * 64 + qg * 16 + l16) * F];
        qf[qg][0] = *(const bf16x8*)&qrow[quad * 8];
        qf[qg][1] = *(const bf16x8*)&qrow[32 + quad * 8];
    }

    f32x4 oacc[4][4];
#pragma unroll
    for (int ft = 0; ft < 4; ++ft)
#pragma unroll
        for (int qg = 0; qg < 4; ++qg) oacc[ft][qg] = (f32x4){0.f, 0.f, 0.f, 0.f};

    const int kb_lo = ks * (N / 64 / KSPLIT);
    const int kb_hi = kb_lo + (N / 64 / KSPLIT);

    // staging unit: u in {tid, tid+256}; r8 = u>>3, c8 = (u&7)*8
    const int r8a = tid >> 3,          c8a = (tid & 7) * 8;
    const int r8b = (tid + 256) >> 3,  c8b = c8a;

    bf16x8 kv0, kv1, gv0, gv1;
    {
        const int k0 = kb_lo * 64;
        kv0 = *(const bf16x8*)&Kb[((size_t)t * N + k0 + r8a) * F + c8a];
        kv1 = *(const bf16x8*)&Kb[((size_t)t * N + k0 + r8b) * F + c8b];
        gv0 = *(const bf16x8*)&Gw[((size_t)t * F + r8a) * (size_t)N + k0 + c8a];
        gv1 = *(const bf16x8*)&Gw[((size_t)t * F + r8b) * (size_t)N + k0 + c8b];
    }

    for (int kb = kb_lo; kb < kb_hi; ++kb) {
        __syncthreads();   // previous tile's LDS reads done
        *(bf16x8*)&Kt[r8a * KS + c8a] = kv0;
        *(bf16x8*)&Kt[r8b * KS + c8b] = kv1;
        *(bf16x8*)&Gt[r8a * KS + c8a] = gv0;
        *(bf16x8*)&Gt[r8b * KS + c8b] = gv1;
        __syncthreads();

        if (kb + 1 < kb_hi) {   // prefetch next tile (overlaps compute)
            const int k0 = (kb + 1) * 64;
            kv0 = *(const bf16x8*)&Kb[((size_t)t * N + k0 + r8a) * F + c8a];
            kv1 = *(const bf16x8*)&Kb[((size_t)t * N + k0 + r8b) * F + c8b];
            gv0 = *(const bf16x8*)&Gw[((size_t)t * F + r8a) * (size_t)N + k0 + c8a];
            gv1 = *(const bf16x8*)&Gw[((size_t)t * F + r8b) * (size_t)N + k0 + c8b];
        }

        // Sᵀ = relu(K·Qᵀ): D[m=key][n=q]; K-frags shared across 4 q-groups
#pragma unroll
        for (int nt = 0; nt < 4; ++nt) {
            bf16x8 k0f = *(const bf16x8*)&Kt[(nt * 16 + l16) * KS + quad * 8];
            bf16x8 k1f = *(const bf16x8*)&Kt[(nt * 16 + l16) * KS + 32 + quad * 8];
#pragma unroll
            for (int qg = 0; qg < 4; ++qg) {
                f32x4 s = (f32x4){0.f, 0.f, 0.f, 0.f};
                s = __builtin_amdgcn_mfma_f32_16x16x32_bf16(k0f, qf[qg][0], s, 0, 0, 0);
                s = __builtin_amdgcn_mfma_f32_16x16x32_bf16(k1f, qf[qg][1], s, 0, 0, 0);
                // D: col=q=l16, row=key=nt*16+quad*4+r -> b64 store to Sb[q][key]
                bf16x4 sp;
#pragma unroll
                for (int r = 0; r < 4; ++r) sp[r] = (__bf16)fmaxf(s[r], 0.f);
                *(bf16x4*)&Sb[(wave * 64 + qg * 16 + l16) * KS + nt * 16 + quad * 4] = sp;
            }
        }

        // PV: Oᵀ[f][q] — wave reads only its own 64 Sb rows (no barrier)
        bf16x8 sf[4][2];
#pragma unroll
        for (int qg = 0; qg < 4; ++qg) {
            const __bf16* srow = &Sb[(wave * 64 + qg * 16 + l16) * KS];
            sf[qg][0] = *(const bf16x8*)&srow[quad * 8];
            sf[qg][1] = *(const bf16x8*)&srow[32 + quad * 8];
        }
#pragma unroll
        for (int ft = 0; ft < 4; ++ft) {
            bf16x8 g0 = *(const bf16x8*)&Gt[(ft * 16 + l16) * KS + quad * 8];
            bf16x8 g1 = *(const bf16x8*)&Gt[(ft * 16 + l16) * KS + 32 + quad * 8];
#pragma unroll
            for (int qg = 0; qg < 4; ++qg) {
                oacc[ft][qg] = __builtin_amdgcn_mfma_f32_16x16x32_bf16(g0, sf[qg][0], oacc[ft][qg], 0, 0, 0);
                oacc[ft][qg] = __builtin_amdgcn_mfma_f32_16x16x32_bf16(g1, sf[qg][1], oacc[ft][qg], 0, 0, 0);
            }
        }
    }

    // Epilogue: D row = f = ft*16+quad*4+r, col = q = q0+wave*64+qg*16+l16
#pragma unroll
    for (int ft = 0; ft < 4; ++ft)
#pragma unroll
        for (int qg = 0; qg < 4; ++qg)
#pragma unroll
            for (int r = 0; r < 4; ++r) {
                int f = ft * 16 + quad * 4 + r;
                int q = q0 + wave * 64 + qg * 16 + l16;
                unsafeAtomicAdd(&out[((size_t)t * F + f) * (size_t)N + q], oacc[ft][qg][r]);
            }
}

// ---------------------------------------------------------------------------
extern "C" void kernel_launch(void* const* d_in, const int* in_sizes, int n_in,
                              void* d_out, int out_size, void* d_ws, size_t ws_size,
                              hipStream_t stream) {
    const float* x1 = (const float*)d_in[0];
    const float* x2 = (const float*)d_in[1];
    const float* W1 = (const float*)d_in[2];
    const float* b1 = (const float*)d_in[3];
    const float* W2 = (const float*)d_in[4];
    const float* b2 = (const float*)d_in[5];
    const float* W3 = (const float*)d_in[6];
    const float* b3 = (const float*)d_in[7];
    float* out = (float*)d_out;

    // workspace: Q [t][n][F], K [t][n][F], G [t][f][N] bf16 (3 x 4 MiB)
    __bf16* Qb = (__bf16*)d_ws;
    __bf16* Kb = Qb + (size_t)T * N * F;
    __bf16* Gw = Kb + (size_t)T * N * F;

    proj_kernel<<<dim3(T * (N / 64)), dim3(256), 0, stream>>>(
        x1, x2, W1, b1, W2, b2, W3, b3, Qb, Kb, Gw, out);
    attn_kernel<<<dim3(T * 16 * KSPLIT), dim3(256), 0, stream>>>(Qb, Kb, Gw, out);
}